// Round 7
// baseline (1422.743 us; speedup 1.0000x reference)
//
#include <hip/hip_runtime.h>
#include <hip/hip_fp16.h>
#include <math.h>

#define NN 20000
#define EE 200000
#define CHUNK_E 28672           // multiple of 64; ef chunk = 29.36 MB
// MUL=128, D=512, EDGE_ATTR=32, HID=32

__device__ __forceinline__ float sspf(float x){
    float sp = (x > 20.f) ? x : log1pf(expf(x));
    return sp - 0.69314718056f;
}

__device__ __forceinline__ void fma8(float* acc, const float* base, float w){
    const float4 a = ((const float4*)base)[0];
    const float4 b = ((const float4*)base)[1];
    acc[0]+=a.x*w; acc[1]+=a.y*w; acc[2]+=a.z*w; acc[3]+=a.w*w;
    acc[4]+=b.x*w; acc[5]+=b.y*w; acc[6]+=b.z*w; acc[7]+=b.w*w;
}

// ---------------- K1: pre irrep_linear -> p1, sdst (p0 consumed in-LDS) ----
__global__ __launch_bounds__(256) void k_pre(
    const float* __restrict__ x, const float* __restrict__ Wp0,
    const float* __restrict__ bp0, const float* __restrict__ Wp1,
    const float* __restrict__ Ws1,
    float* __restrict__ p1, float* __restrict__ sdst)
{
    __shared__ float xl[512][8];    // transposed [feature][node]
    __shared__ float p0l[8][128];
    const int tid = threadIdx.x;
    const int n0 = blockIdx.x * 8;

    for (int it = 0; it < 4; ++it){
        int idx = tid + 256*it;           // 0..1023 float4 slots
        int node = idx >> 7, o4 = idx & 127;
        float4 v = ((const float4*)(x + (size_t)(n0+node)*512))[o4];
        xl[o4*4+0][node]=v.x; xl[o4*4+1][node]=v.y;
        xl[o4*4+2][node]=v.z; xl[o4*4+3][node]=v.w;
    }
    __syncthreads();

    const int j = tid;
    float acc1[8] = {0,0,0,0,0,0,0,0};
    float acc2[8] = {0,0,0,0,0,0,0,0};
    const int o2 = j + 128;               // p1-index in [128,384)
    const int v2 = o2/3, m2 = o2%3;

    if (j < 128){
        for (int u = 0; u < 128; ++u){
            float w1 = Wp0[u*128 + j];
            float w2 = Wp1[u*128 + v2];
            fma8(acc1, &xl[u][0], w1);
            fma8(acc2, &xl[128 + u*3 + m2][0], w2);
        }
        float b = bp0[j];
        #pragma unroll
        for (int n = 0; n < 8; ++n) p0l[n][j] = acc1[n] + b;
    } else {
        const int o1 = j - 128, v1 = o1/3, m1 = o1%3;
        for (int u = 0; u < 128; ++u){
            float w1 = Wp1[u*128 + v1];
            float w2 = Wp1[u*128 + v2];
            fma8(acc1, &xl[128 + u*3 + m1][0], w1);
            fma8(acc2, &xl[128 + u*3 + m2][0], w2);
        }
        #pragma unroll
        for (int n = 0; n < 8; ++n) p1[(size_t)(n0+n)*384 + (j-128)] = acc1[n];
    }
    #pragma unroll
    for (int n = 0; n < 8; ++n) p1[(size_t)(n0+n)*384 + o2] = acc2[n];
    __syncthreads();

    // sdst = p0 @ (Ws1[0:128] + Ws1[128:256])  (the dst-only part of s0@W_s1)
    {
        int n = tid >> 5, h = tid & 31;
        float s = 0.f;
        for (int u = 0; u < 128; ++u){
            float wc = Ws1[u*32 + h] + Ws1[(128+u)*32 + h];
            s += p0l[n][u] * wc;
        }
        sdst[(size_t)(n0+n)*32 + h] = s;
    }
}

// ---------------- K2: gate + node irrep_linear -> self_x -------------------
__global__ __launch_bounds__(256) void k_gate_nd(
    const float* __restrict__ x,
    const float* __restrict__ Wg1, const float* __restrict__ bg1,
    const float* __restrict__ Wg2, const float* __restrict__ bg2,
    const float* __restrict__ Wnd0, const float* __restrict__ bnd0,
    const float* __restrict__ Wnd1,
    float* __restrict__ self_x)
{
    __shared__ float xl[512][8];
    __shared__ float tl[256][8];   // t, then reused for g
    __shared__ float hl[256][8];
    const int tid = threadIdx.x;
    const int n0 = blockIdx.x * 8;

    for (int it = 0; it < 4; ++it){
        int idx = tid + 256*it;
        int node = idx >> 7, o4 = idx & 127;
        float4 v = ((const float4*)(x + (size_t)(n0+node)*512))[o4];
        xl[o4*4+0][node]=v.x; xl[o4*4+1][node]=v.y;
        xl[o4*4+2][node]=v.z; xl[o4*4+3][node]=v.w;
    }
    __syncthreads();

    { // t = [x0, n1]
        int jj = tid;
        if (jj < 128){
            #pragma unroll
            for (int n = 0; n < 8; ++n) tl[jj][n] = xl[jj][n];
        } else {
            int u = jj - 128;
            #pragma unroll
            for (int n = 0; n < 8; ++n){
                float a = xl[128+u*3][n], b = xl[128+u*3+1][n], c = xl[128+u*3+2][n];
                tl[jj][n] = sqrtf((a*a + b*b + c*c) * (1.f/3.f));
            }
        }
    }
    __syncthreads();

    { // h = silu(t @ Wg1 + bg1)
        float acc[8] = {0,0,0,0,0,0,0,0};
        for (int k = 0; k < 256; ++k){
            float w = Wg1[k*256 + tid];
            fma8(acc, &tl[k][0], w);
        }
        float b = bg1[tid];
        #pragma unroll
        for (int n = 0; n < 8; ++n){
            float v = acc[n] + b;
            hl[tid][n] = v / (1.f + expf(-v));
        }
    }
    __syncthreads();

    { // g = h @ Wg2 + bg2  (stored into tl; tl is dead after the barrier)
        float acc[8] = {0,0,0,0,0,0,0,0};
        for (int k = 0; k < 256; ++k){
            float w = Wg2[k*256 + tid];
            fma8(acc, &hl[k][0], w);
        }
        float b = bg2[tid];
        #pragma unroll
        for (int n = 0; n < 8; ++n) tl[tid][n] = acc[n] + b;
    }
    __syncthreads();

    { // xg in-place into xl
        int jj = tid;
        if (jj < 128){
            #pragma unroll
            for (int n = 0; n < 8; ++n) xl[jj][n] = tl[jj][n];
        } else {
            int u = jj - 128;
            #pragma unroll
            for (int n = 0; n < 8; ++n){
                float g1 = tl[128+u][n];
                xl[128+u*3  ][n] *= g1;
                xl[128+u*3+1][n] *= g1;
                xl[128+u*3+2][n] *= g1;
            }
        }
    }
    __syncthreads();

    // nd irrep_linear
    const int j = tid;
    float acc1[8] = {0,0,0,0,0,0,0,0};
    float acc2[8] = {0,0,0,0,0,0,0,0};
    const int o2 = j + 128;
    const int v2 = o2/3, m2 = o2%3;
    if (j < 128){
        for (int u = 0; u < 128; ++u){
            float w1 = Wnd0[u*128 + j];
            float w2 = Wnd1[u*128 + v2];
            fma8(acc1, &xl[u][0], w1);
            fma8(acc2, &xl[128 + u*3 + m2][0], w2);
        }
        float b = bnd0[j];
        #pragma unroll
        for (int n = 0; n < 8; ++n) self_x[(size_t)(n0+n)*512 + j] = acc1[n] + b;
    } else {
        const int o1 = j - 128, v1 = o1/3, m1 = o1%3;
        for (int u = 0; u < 128; ++u){
            float w1 = Wnd1[u*128 + v1];
            float w2 = Wnd1[u*128 + v2];
            fma8(acc1, &xl[128 + u*3 + m1][0], w1);
            fma8(acc2, &xl[128 + u*3 + m2][0], w2);
        }
        #pragma unroll
        for (int n = 0; n < 8; ++n) self_x[(size_t)(n0+n)*512 + j] = acc1[n];
    }
    #pragma unroll
    for (int n = 0; n < 8; ++n) self_x[(size_t)(n0+n)*512 + j + 256] = acc2[n];
}

// ---------------- K3: edge features -> fbuf, sbuf (E x 32 each) ------------
__global__ __launch_bounds__(256) void k_edge_pre(
    const float* __restrict__ p1g, const float* __restrict__ sdst,
    const float* __restrict__ ea, const int* __restrict__ eidx,
    const float* __restrict__ Wf1, const float* __restrict__ Ws1,
    float* __restrict__ fbuf, float* __restrict__ sbuf)
{
    __shared__ float p1d[8][384], p1s[8][384];
    __shared__ float eal[8][32], sdl[8][32];
    __shared__ float ip1l[8][128];
    __shared__ int il[8][2];
    const int tid = threadIdx.x;
    const long e0 = (long)blockIdx.x * 8;

    if (tid < 16){
        int e = tid & 7;
        il[e][tid>>3] = eidx[(size_t)(tid>>3)*EE + e0 + e];
    }
    __syncthreads();

    for (int e = 0; e < 8; ++e){
        int dst = il[e][0], src = il[e][1];
        if (tid < 96)
            ((float4*)p1d[e])[tid] = ((const float4*)(p1g + (size_t)dst*384))[tid];
        else if (tid < 192)
            ((float4*)p1s[e])[tid-96] = ((const float4*)(p1g + (size_t)src*384))[tid-96];
        else if (tid < 200)
            ((float4*)eal[e])[tid-192] = ((const float4*)(ea + (e0+e)*32))[tid-192];
        else if (tid < 208)
            ((float4*)sdl[e])[tid-200] = ((const float4*)(sdst + (size_t)dst*32))[tid-200];
    }
    __syncthreads();

    for (int it = 0; it < 4; ++it){
        int idx = tid + 256*it;
        int e = idx >> 7, u = idx & 127;
        ip1l[e][u] = (p1d[e][u*3]*p1s[e][u*3] + p1d[e][u*3+1]*p1s[e][u*3+1]
                    + p1d[e][u*3+2]*p1s[e][u*3+2]) * (1.f/3.f);
    }
    __syncthreads();

    {
        int e = tid >> 5, h = tid & 31;
        float f = 0.f;
        for (int k = 0; k < 32; ++k) f += eal[e][k] * Wf1[k*32 + h];
        float s = sdl[e][h];
        for (int u = 0; u < 128; ++u) s += ip1l[e][u] * Ws1[(256+u)*32 + h];
        fbuf[(e0+e)*32 + h] = sspf(f);
        sbuf[(e0+e)*32 + h] = sspf(s);
    }
}

// ---------------- CSR build: count, scan, fill -----------------------------
__global__ __launch_bounds__(256) void k_count(
    const int* __restrict__ eidx, int* __restrict__ cnt)
{
    int e = blockIdx.x * 256 + threadIdx.x;
    if (e < EE){
        int d = eidx[e];
        if (d >= 0 && d < NN) atomicAdd(&cnt[d], 1);
    }
}

__global__ __launch_bounds__(256) void k_scan(
    const int* __restrict__ cnt, int* __restrict__ rowptr, int* __restrict__ cur)
{
    __shared__ int part[256];
    const int t = threadIdx.x;
    const int CHUNK = 79;             // 256*79 = 20224 >= 20000
    const int base = t * CHUNK;
    int s = 0;
    for (int i = 0; i < CHUNK; ++i){
        int idx = base + i;
        if (idx < NN) s += cnt[idx];
    }
    part[t] = s;
    __syncthreads();
    for (int off = 1; off < 256; off <<= 1){
        int v = (t >= off) ? part[t-off] : 0;
        __syncthreads();
        part[t] += v;
        __syncthreads();
    }
    int run = (t == 0) ? 0 : part[t-1];
    for (int i = 0; i < CHUNK; ++i){
        int idx = base + i;
        if (idx < NN){
            rowptr[idx] = run;
            cur[idx]    = run;
            run += cnt[idx];
        }
    }
    if (t == 255) rowptr[NN] = run;
}

__global__ __launch_bounds__(256) void k_fill(
    const int* __restrict__ eidx, int* __restrict__ cur, int2* __restrict__ ebuf)
{
    int e = blockIdx.x * 256 + threadIdx.x;
    if (e < EE){
        int dst = eidx[e];
        int src = eidx[EE + e];
        if (dst >= 0 && dst < NN){
            int pos = atomicAdd(&cur[dst], 1);
            if (pos >= 0 && pos < EE) ebuf[pos] = make_int2(e, src);
        }
    }
}

// ---------------- edge GEMM: 64 CSR edges/block -> fp16 ef chunk -----------
// lanes = edges; wave wv owns channel strip [32*wv, 32*wv+32).
// Weight addresses are wave-uniform -> scalar loads.
__device__ __forceinline__ void qdot(
    const float* __restrict__ W2f, const float* __restrict__ W2s,
    const float (*fbl)[33], const float (*sbl)[33],
    int lane, int q, int wv, float* wout /*32*/)
{
    float F[32], S[32];
    #pragma unroll
    for (int c = 0; c < 32; ++c){ F[c] = 0.f; S[c] = 0.f; }
    const float* wfp = W2f + q*128 + wv*32;
    const float* wsp = W2s + q*128 + wv*32;
    for (int k = 0; k < 32; ++k){
        float fb = fbl[lane][k];
        float sb = sbl[lane][k];
        const float* wf = wfp + (size_t)k*512;
        const float* ws = wsp + (size_t)k*512;
        #pragma unroll
        for (int c = 0; c < 32; ++c){
            F[c] += fb * wf[c];
            S[c] += sb * ws[c];
        }
    }
    #pragma unroll
    for (int c = 0; c < 32; ++c) wout[c] = F[c] * S[c];
}

__global__ __launch_bounds__(256) void k_w_edge(
    const float* __restrict__ fbuf, const float* __restrict__ sbuf,
    const float* __restrict__ self_x, const float* __restrict__ esh,
    const int2* __restrict__ ebuf, int eb0,
    const float* __restrict__ Wf2, const float* __restrict__ Ws2,
    __half* __restrict__ ef)
{
    __shared__ int2  il[64];
    __shared__ float fbl[64][33];   // +1 pad: conflict-free lane-spread reads
    __shared__ float sbl[64][33];

    const int tid  = threadIdx.x;
    const int lane = tid & 63;
    const int wv   = __builtin_amdgcn_readfirstlane(tid >> 6); // uniform strip id
    const int eloc = blockIdx.x * 64;     // chunk-local edge base

    if (tid < 64){
        int2 pe = ebuf[(size_t)eb0 + eloc + tid];
        if (!(pe.x >= 0 && pe.x < EE)) pe.x = 0;   // defensive (poison-safe)
        if (!(pe.y >= 0 && pe.y < NN)) pe.y = 0;
        il[tid] = pe;
    }
    __syncthreads();

    for (int it = 0; it < 8; ++it){
        int idx = tid + 256*it;      // 0..2047
        int e = idx >> 5, k = idx & 31;
        int eid = il[e].x;
        fbl[e][k] = fbuf[(size_t)eid*32 + k];
        sbl[e][k] = sbuf[(size_t)eid*32 + k];
    }
    __syncthreads();

    const int eid = il[lane].x;
    const int src = il[lane].y;
    const float4 sh = ((const float4*)esh)[eid];
    const float* sx = self_x + (size_t)src * 512;
    __half* efr = ef + (size_t)(eloc + lane) * 512;
    const float IS3 = 0.57735026919f;

    float w1r[32], w4r[32];
    qdot(Wf2, Ws2, fbl, sbl, lane, 0, wv, w1r);
    qdot(Wf2, Ws2, fbl, sbl, lane, 3, wv, w4r);

    // epilogue A: out0 channels [32wv, 32wv+32)
    #pragma unroll
    for (int c4 = 0; c4 < 8; ++c4){
        const int cb = wv*32 + c4*4;       // global channel base
        float4 x0 = *(const float4*)(sx + cb);
        float4 xa = *(const float4*)(sx + 128 + 3*cb);
        float4 xb = *(const float4*)(sx + 128 + 3*cb + 4);
        float4 xc = *(const float4*)(sx + 128 + 3*cb + 8);
        float d0 = xa.x*sh.y + xa.y*sh.z + xa.z*sh.w;
        float d1 = xa.w*sh.y + xb.x*sh.z + xb.y*sh.w;
        float d2 = xb.z*sh.y + xb.w*sh.z + xc.x*sh.w;
        float d3 = xc.y*sh.y + xc.z*sh.z + xc.w*sh.w;
        int i0 = c4*4;
        float o0 = w1r[i0+0]*x0.x*sh.x + w4r[i0+0]*d0*IS3;
        float o1 = w1r[i0+1]*x0.y*sh.x + w4r[i0+1]*d1*IS3;
        float o2 = w1r[i0+2]*x0.z*sh.x + w4r[i0+2]*d2*IS3;
        float o3 = w1r[i0+3]*x0.w*sh.x + w4r[i0+3]*d3*IS3;
        __half2* ep = (__half2*)(efr + cb);
        ep[0] = __floats2half2_rn(o0, o1);
        ep[1] = __floats2half2_rn(o2, o3);
    }

    float w2r[32], w3r[32];
    qdot(Wf2, Ws2, fbl, sbl, lane, 1, wv, w2r);
    qdot(Wf2, Ws2, fbl, sbl, lane, 2, wv, w3r);

    // epilogue B: out1 channels -> positions 128+3c+m
    #pragma unroll
    for (int c4 = 0; c4 < 8; ++c4){
        const int cb = wv*32 + c4*4;
        float4 x0 = *(const float4*)(sx + cb);
        float4 xa = *(const float4*)(sx + 128 + 3*cb);
        float4 xb = *(const float4*)(sx + 128 + 3*cb + 4);
        float4 xc = *(const float4*)(sx + 128 + 3*cb + 8);
        int i0 = c4*4;
        float t0 = w2r[i0+0]*x0.x, g0 = w3r[i0+0]*sh.x;
        float t1 = w2r[i0+1]*x0.y, g1 = w3r[i0+1]*sh.x;
        float t2 = w2r[i0+2]*x0.z, g2 = w3r[i0+2]*sh.x;
        float t3 = w2r[i0+3]*x0.w, g3 = w3r[i0+3]*sh.x;
        float m00 = t0*sh.y + g0*xa.x, m01 = t0*sh.z + g0*xa.y, m02 = t0*sh.w + g0*xa.z;
        float m10 = t1*sh.y + g1*xa.w, m11 = t1*sh.z + g1*xb.x, m12 = t1*sh.w + g1*xb.y;
        float m20 = t2*sh.y + g2*xb.z, m21 = t2*sh.z + g2*xb.w, m22 = t2*sh.w + g2*xc.x;
        float m30 = t3*sh.y + g3*xc.y, m31 = t3*sh.z + g3*xc.z, m32 = t3*sh.w + g3*xc.w;
        __half2* ep = (__half2*)(efr + 128 + 3*cb);
        ep[0] = __floats2half2_rn(m00, m01);
        ep[1] = __floats2half2_rn(m02, m10);
        ep[2] = __floats2half2_rn(m11, m12);
        ep[3] = __floats2half2_rn(m20, m21);
        ep[4] = __floats2half2_rn(m22, m30);
        ep[5] = __floats2half2_rn(m31, m32);
    }
}

// ---------------- chunked segment sum: out[n] += sum(ef rows in chunk) -----
__global__ __launch_bounds__(256) void k_seg_sum(
    const __half* __restrict__ ef, const int* __restrict__ rowptr,
    int c0, int c1, float* __restrict__ out)
{
    const int tid  = threadIdx.x;
    const int lane = tid & 63;
    const int n    = blockIdx.x * 4 + (tid >> 6);
    int start = rowptr[n];
    int end   = rowptr[n+1];
    if (start < c0) start = c0;
    if (end   > c1) end   = c1;
    if (start >= end) return;          // node has no edges in this chunk

    float a[8] = {0,0,0,0,0,0,0,0};
    for (int i = start; i < end; ++i){
        float4 rv = *(const float4*)(ef + (size_t)(i - c0)*512 + lane*8); // 8 halves
        const __half2* hp = (const __half2*)&rv;
        #pragma unroll
        for (int q = 0; q < 4; ++q){
            float2 f = __half22float2(hp[q]);
            a[2*q]   += f.x;
            a[2*q+1] += f.y;
        }
    }
    float* op = out + (size_t)n*512 + lane*8;
    float4 v0 = *(float4*)op;
    float4 v1 = *((float4*)op + 1);
    *(float4*)op       = make_float4(v0.x+a[0], v0.y+a[1], v0.z+a[2], v0.w+a[3]);
    *((float4*)op + 1) = make_float4(v1.x+a[4], v1.y+a[5], v1.z+a[6], v1.w+a[7]);
}

// ---------------- K5: out linear + residual (in-place over d_out) ----------
__global__ __launch_bounds__(256) void k_post(
    const float* __restrict__ self_x, const float* __restrict__ x,
    const float* __restrict__ Wo0, const float* __restrict__ bo0,
    const float* __restrict__ Wo1,
    float* __restrict__ out)
{
    __shared__ float tl[512][8];
    const int tid = threadIdx.x;
    const int n0 = blockIdx.x * 8;

    for (int it = 0; it < 4; ++it){
        int idx = tid + 256*it;
        int node = idx >> 7, o4 = idx & 127;
        float4 a = ((const float4*)(out    + (size_t)(n0+node)*512))[o4];
        float4 b = ((const float4*)(self_x + (size_t)(n0+node)*512))[o4];
        tl[o4*4+0][node]=a.x+b.x; tl[o4*4+1][node]=a.y+b.y;
        tl[o4*4+2][node]=a.z+b.z; tl[o4*4+3][node]=a.w+b.w;
    }
    __syncthreads();

    const int j = tid;
    float acc1[8] = {0,0,0,0,0,0,0,0};
    float acc2[8] = {0,0,0,0,0,0,0,0};
    const int o2 = j + 128;
    const int v2 = o2/3, m2 = o2%3;
    if (j < 128){
        for (int u = 0; u < 128; ++u){
            float w1 = Wo0[u*128 + j];
            float w2 = Wo1[u*128 + v2];
            fma8(acc1, &tl[u][0], w1);
            fma8(acc2, &tl[128 + u*3 + m2][0], w2);
        }
        float b = bo0[j];
        #pragma unroll
        for (int n = 0; n < 8; ++n)
            out[(size_t)(n0+n)*512 + j] = acc1[n] + b + x[(size_t)(n0+n)*512 + j];
    } else {
        const int o1 = j - 128, v1 = o1/3, m1 = o1%3;
        for (int u = 0; u < 128; ++u){
            float w1 = Wo1[u*128 + v1];
            float w2 = Wo1[u*128 + v2];
            fma8(acc1, &tl[128 + u*3 + m1][0], w1);
            fma8(acc2, &tl[128 + u*3 + m2][0], w2);
        }
        #pragma unroll
        for (int n = 0; n < 8; ++n)
            out[(size_t)(n0+n)*512 + j] = acc1[n] + x[(size_t)(n0+n)*512 + j];
    }
    #pragma unroll
    for (int n = 0; n < 8; ++n)
        out[(size_t)(n0+n)*512 + j + 256] = acc2[n] + x[(size_t)(n0+n)*512 + j + 256];
}

// ---------------------------------------------------------------------------
extern "C" void kernel_launch(void* const* d_in, const int* in_sizes, int n_in,
                              void* d_out, int out_size, void* d_ws, size_t ws_size,
                              hipStream_t stream)
{
    const float* x    = (const float*)d_in[0];
    const float* esh  = (const float*)d_in[1];
    const float* ea   = (const float*)d_in[2];
    const int*   eidx = (const int*)  d_in[3];
    const float* Wp0  = (const float*)d_in[4];
    const float* bp0  = (const float*)d_in[5];
    const float* Wp1  = (const float*)d_in[6];
    const float* Wnd0 = (const float*)d_in[7];
    const float* bnd0 = (const float*)d_in[8];
    const float* Wnd1 = (const float*)d_in[9];
    const float* Wg1  = (const float*)d_in[10];
    const float* bg1  = (const float*)d_in[11];
    const float* Wg2  = (const float*)d_in[12];
    const float* bg2  = (const float*)d_in[13];
    const float* Wf1  = (const float*)d_in[14];
    const float* Wf2  = (const float*)d_in[15];
    const float* Ws1  = (const float*)d_in[16];
    const float* Ws2  = (const float*)d_in[17];
    const float* Wo0  = (const float*)d_in[18];
    const float* bo0  = (const float*)d_in[19];
    const float* Wo1  = (const float*)d_in[20];

    float* out  = (float*)d_out;
    float* ws   = (float*)d_ws;
    // Layout (total 125.44 MB, same envelope as the passing round-1 run):
    float* p1   = ws;                              // N*384 (dead after k_edge_pre)
    float* sdst = p1   + (size_t)NN*384;           // N*32  (dead after k_edge_pre)
    float* sfx  = sdst + (size_t)NN*32;            // N*512
    float* fbuf = sfx  + (size_t)NN*512;           // E*32
    float* sbuf = fbuf + (size_t)EE*32;            // E*32

    // CSR + ef chunk overlay the dead p1+sdst region (33.28 MB):
    //   CSR: [0, 1.84 MB) ; ef chunk: [2 MB, 2 MB + 29.36 MB) < 33.28 MB
    int*  cnt    = (int*)p1;
    int*  rowptr = cnt + NN;              // N+1
    int*  cur    = rowptr + NN + 1;       // N
    int2* ebuf   = (int2*)(cur + NN + 1); // E int2 (byte offset 240008, 8-aligned)
    __half* ef   = (__half*)((char*)d_ws + (size_t)2*1024*1024); // 16B-aligned

    hipMemsetAsync(d_out, 0, (size_t)NN*512*sizeof(float), stream);

    k_pre     <<<NN/8, 256, 0, stream>>>(x, Wp0, bp0, Wp1, Ws1, p1, sdst);
    k_gate_nd <<<NN/8, 256, 0, stream>>>(x, Wg1, bg1, Wg2, bg2, Wnd0, bnd0, Wnd1, sfx);
    k_edge_pre<<<EE/8, 256, 0, stream>>>(p1, sdst, ea, eidx, Wf1, Ws1, fbuf, sbuf);

    // p1/sdst now dead — build CSR in their place
    hipMemsetAsync(cnt, 0, (size_t)NN*sizeof(int), stream);
    k_count <<<(EE+255)/256, 256, 0, stream>>>(eidx, cnt);
    k_scan  <<<1, 256, 0, stream>>>(cnt, rowptr, cur);
    k_fill  <<<(EE+255)/256, 256, 0, stream>>>(eidx, cur, ebuf);

    // chunked edge GEMM + segment sum (ef chunk reused across chunks)
    for (int c0 = 0; c0 < EE; c0 += CHUNK_E){
        int c1 = c0 + CHUNK_E; if (c1 > EE) c1 = EE;
        int nblk = (c1 - c0) / 64;          // chunk sizes are multiples of 64
        k_w_edge  <<<nblk, 256, 0, stream>>>(fbuf, sbuf, sfx, esh, ebuf, c0,
                                             Wf2, Ws2, ef);
        k_seg_sum <<<NN/4, 256, 0, stream>>>(ef, rowptr, c0, c1, out);
    }

    k_post    <<<NN/8, 256, 0, stream>>>(sfx, x, Wo0, bo0, Wo1, out);
}